// Round 1
// baseline (777.952 us; speedup 1.0000x reference)
//
#include <hip/hip_runtime.h>

#define DIM 256

typedef float f4 __attribute__((ext_vector_type(4)));

// One 64-lane wave per edge. Lane l holds float4 covering elements [4l, 4l+4).
// score = 0.5 * sum_k r[k] * h[k] * t[(k+128) mod 256]  (fwd/bwd halves fused)
//
// rel_emb is 512 MB of use-once stream data (2x the 256 MB L3); load it
// non-temporally so it does not evict the 102 MB node_emb gather table
// from L2/L3. node_emb loads stay on the normal (caching) path.
__global__ void __launch_bounds__(256) simple_score_kernel(
    const float* __restrict__ node_emb,
    const float* __restrict__ rel_emb,
    const int* __restrict__ src,
    const int* __restrict__ dst,
    float* __restrict__ out,
    int n_edges)
{
    const int wave = (int)((blockIdx.x * (unsigned)blockDim.x + threadIdx.x) >> 6);
    const int lane = (int)(threadIdx.x & 63u);
    if (wave >= n_edges) return;

    const long long s = src[wave];
    const long long d = dst[wave];

    const f4* __restrict__ h4 = (const f4*)(node_emb + s * DIM);
    const f4* __restrict__ t4 = (const f4*)(node_emb + d * DIM);
    const f4* __restrict__ r4 = (const f4*)(rel_emb + (long long)wave * DIM);

    // Caching loads for the gathered node table (we WANT these resident).
    const f4 h = h4[lane];
    // t rotated by 128 floats = 32 float4s (mod 64)
    const f4 t = t4[(lane + 32) & 63];
    // Streaming (non-temporal) load for the use-once rel stream.
    const f4 r = __builtin_nontemporal_load(r4 + lane);

    float p = h.x * r.x * t.x;
    p = fmaf(h.y * r.y, t.y, p);
    p = fmaf(h.z * r.z, t.z, p);
    p = fmaf(h.w * r.w, t.w, p);

    // 64-lane wave reduction
    #pragma unroll
    for (int off = 32; off > 0; off >>= 1)
        p += __shfl_down(p, off, 64);

    if (lane == 0) {
        float sc = 0.5f * p;
        sc = fminf(fmaxf(sc, -20.0f), 20.0f);
        __builtin_nontemporal_store(sc, &out[wave]);
    }
}

extern "C" void kernel_launch(void* const* d_in, const int* in_sizes, int n_in,
                              void* d_out, int out_size, void* d_ws, size_t ws_size,
                              hipStream_t stream) {
    const float* node_emb = (const float*)d_in[0];
    const float* rel_emb  = (const float*)d_in[1];
    const int*   src      = (const int*)d_in[2];
    const int*   dst      = (const int*)d_in[3];
    float* out = (float*)d_out;

    const int n_edges = in_sizes[2];       // E = 500000
    const int waves_per_block = 256 / 64;  // 4 edges per block
    const int blocks = (n_edges + waves_per_block - 1) / waves_per_block;

    simple_score_kernel<<<blocks, 256, 0, stream>>>(
        node_emb, rel_emb, src, dst, out, n_edges);
}